// Round 1
// baseline (6205.558 us; speedup 1.0000x reference)
//
#include <hip/hip_runtime.h>
#include <hip/hip_bf16.h>

#define DEV static __device__ __forceinline__

namespace {
constexpr int kV = 27, kE = 64, kH = 100, kS = 10, kB = 32768;
constexpr int G3 = 3 * kH;        // 300
constexpr int BT = 64;            // batch rows per block
constexpr int DQ = 25;            // hidden dims per quarter (4*25 = 100)
constexpr int KX_D = kE + kH;     // 164 (decoder input = [x, ctx])

// ---- workspace layout (float offsets) ----
constexpr int OFF_WIHT_E = 0;                      // [64][300]  k-major
constexpr int OFF_WHHT_E = OFF_WIHT_E + kE * G3;   // [100][300]
constexpr int OFF_WIHT_D = OFF_WHHT_E + kH * G3;   // [164][300]
constexpr int OFF_WHHT_D = OFF_WIHT_D + KX_D * G3; // [100][300]
constexpr int OFF_LINT   = OFF_WHHT_D + kH * G3;   // [100][27]
constexpr int OFF_BE     = OFF_LINT + kH * kV;     // br,bz,bnx,bnh (4*100)
constexpr int OFF_BD     = OFF_BE + 4 * kH;        // same, decoder
constexpr int OFF_ENC    = OFF_BD + 4 * kH;        // bf16 enc_out [512][10][100][64]
} // namespace

DEV float sigm(float x) { return 1.f / (1.f + __expf(-x)); }
DEV float tanh_(float x) {
  const float ax = fabsf(x);
  const float t = __expf(-2.f * ax);
  const float r = (1.f - t) / (1.f + t);
  return copysignf(r, x);
}

// ---- setup: transpose weights to k-major, fold biases ----
__global__ void seq2seq_setup(const float* __restrict__ eWih, const float* __restrict__ eWhh,
                              const float* __restrict__ ebih, const float* __restrict__ ebhh,
                              const float* __restrict__ dWih, const float* __restrict__ dWhh,
                              const float* __restrict__ dbih, const float* __restrict__ dbhh,
                              const float* __restrict__ linW, float* __restrict__ ws) {
  const int tid = blockIdx.x * blockDim.x + threadIdx.x;
  const int stride = gridDim.x * blockDim.x;
  for (int t = tid; t < kE * G3; t += stride) { int k = t / G3, d = t - k * G3; ws[OFF_WIHT_E + t] = eWih[d * kE + k]; }
  for (int t = tid; t < kH * G3; t += stride) { int k = t / G3, d = t - k * G3; ws[OFF_WHHT_E + t] = eWhh[d * kH + k]; }
  for (int t = tid; t < KX_D * G3; t += stride) { int k = t / G3, d = t - k * G3; ws[OFF_WIHT_D + t] = dWih[d * KX_D + k]; }
  for (int t = tid; t < kH * G3; t += stride) { int k = t / G3, d = t - k * G3; ws[OFF_WHHT_D + t] = dWhh[d * kH + k]; }
  for (int t = tid; t < kH * kV; t += stride) { int k = t / kV, v = t - k * kV; ws[OFF_LINT + t] = linW[v * kH + k]; }
  for (int t = tid; t < kH; t += stride) {
    ws[OFF_BE + t]          = ebih[t] + ebhh[t];
    ws[OFF_BE + kH + t]     = ebih[kH + t] + ebhh[kH + t];
    ws[OFF_BE + 2 * kH + t] = ebih[2 * kH + t];
    ws[OFF_BE + 3 * kH + t] = ebhh[2 * kH + t];
    ws[OFF_BD + t]          = dbih[t] + dbhh[t];
    ws[OFF_BD + kH + t]     = dbih[kH + t] + dbhh[kH + t];
    ws[OFF_BD + 2 * kH + t] = dbih[2 * kH + t];
    ws[OFF_BD + 3 * kH + t] = dbhh[2 * kH + t];
  }
}

// ---- fused encoder + attention-decoder + logits ----
// block = 256 threads = 64 rows x 4 wave-uniform quarters; grid = 512 blocks.
__launch_bounds__(256, 2)
__global__ void seq2seq_main(const int* __restrict__ encX, const int* __restrict__ decX,
                             const float* __restrict__ emb, const float* __restrict__ attnW,
                             const float* __restrict__ linb, float* __restrict__ ws,
                             float* __restrict__ out) {
  const int tid = threadIdx.x;
  const int r = tid & 63;                                   // row in tile (lane)
  const int q = __builtin_amdgcn_readfirstlane(tid >> 6);   // wave-uniform quarter
  const int d0 = q * DQ;
  const int blk = blockIdx.x;
  const int b = blk * BT + r;

  __shared__ float h_lds[BT][kH + 1];            // +1 pad: conflict-free broadcast reads
  __shared__ __hip_bfloat16 xc[BT][KX_D + 2];    // [x | ctx], stride 166 (odd word stride)
  __shared__ float scp[BT][4][kS];               // per-quarter partial scores
  __shared__ float emb_lds[kV * kE];

  for (int i = tid; i < kV * kE; i += 256) emb_lds[i] = emb[i];
#pragma unroll
  for (int j = 0; j < DQ; ++j) h_lds[r][d0 + j] = 0.f;
  __syncthreads();

  const float* WihT_e = ws + OFF_WIHT_E;
  const float* WhhT_e = ws + OFF_WHHT_E;
  const float* WihT_d = ws + OFF_WIHT_D;
  const float* WhhT_d = ws + OFF_WHHT_D;
  const float* linT   = ws + OFF_LINT;
  const float* be     = ws + OFF_BE;
  const float* bd     = ws + OFF_BD;
  __hip_bfloat16* encb = reinterpret_cast<__hip_bfloat16*>(ws + OFF_ENC);

  // ================= encoder =================
  for (int t = 0; t < kS; ++t) {
    const int idx = encX[b * kS + t];
#pragma unroll
    for (int i = 0; i < 16; ++i)
      xc[r][q * 16 + i] = __float2bfloat16(emb_lds[idx * kE + q * 16 + i]);
    __syncthreads();

    float ar[DQ], az[DQ], anx[DQ], anh[DQ];
#pragma unroll
    for (int j = 0; j < DQ; ++j) {
      ar[j] = be[d0 + j]; az[j] = be[kH + d0 + j];
      anx[j] = be[2 * kH + d0 + j]; anh[j] = be[3 * kH + d0 + j];
    }
    for (int k = 0; k < kE; ++k) {                 // gx: weights via scalar loads (uniform addr)
      const float xv = __bfloat162float(xc[r][k]);
      const float* w = WihT_e + k * G3 + d0;
#pragma unroll
      for (int j = 0; j < DQ; ++j) {
        ar[j]  = fmaf(w[j], xv, ar[j]);
        az[j]  = fmaf(w[kH + j], xv, az[j]);
        anx[j] = fmaf(w[2 * kH + j], xv, anx[j]);
      }
    }
    for (int k = 0; k < kH; ++k) {                 // gh
      const float hv = h_lds[r][k];
      const float* w = WhhT_e + k * G3 + d0;
#pragma unroll
      for (int j = 0; j < DQ; ++j) {
        ar[j]  = fmaf(w[j], hv, ar[j]);
        az[j]  = fmaf(w[kH + j], hv, az[j]);
        anh[j] = fmaf(w[2 * kH + j], hv, anh[j]);
      }
    }
    float hn[DQ];
#pragma unroll
    for (int j = 0; j < DQ; ++j) {
      const float rg = sigm(ar[j]);
      const float zg = sigm(az[j]);
      const float ng = tanh_(anx[j] + rg * anh[j]);
      hn[j] = (1.f - zg) * ng + zg * h_lds[r][d0 + j];
    }
    __syncthreads();
#pragma unroll
    for (int j = 0; j < DQ; ++j) {
      h_lds[r][d0 + j] = hn[j];
      encb[((blk * kS + t) * kH + d0 + j) * BT + r] = __float2bfloat16(hn[j]);  // coalesced
    }
    __syncthreads();
  }

  // ================= decoder =================
  for (int t = 0; t < kS; ++t) {
    const int idx = decX[b * kS + t];
#pragma unroll
    for (int i = 0; i < 16; ++i)
      xc[r][q * 16 + i] = __float2bfloat16(emb_lds[idx * kE + q * 16 + i]);

    // g = h @ attn_W, own 25 dims kept in registers
    float gv[DQ];
#pragma unroll
    for (int j = 0; j < DQ; ++j) gv[j] = 0.f;
    for (int i = 0; i < kH; ++i) {
      const float hv = h_lds[r][i];
      const float* w = attnW + i * kH + d0;
#pragma unroll
      for (int j = 0; j < DQ; ++j) gv[j] = fmaf(w[j], hv, gv[j]);
    }
    // partial scores over own quarter
#pragma unroll
    for (int s = 0; s < kS; ++s) {
      float acc = 0.f;
      const __hip_bfloat16* er = encb + ((blk * kS + s) * kH + d0) * BT + r;
#pragma unroll
      for (int j = 0; j < DQ; ++j) acc = fmaf(__bfloat162float(er[j * BT]), gv[j], acc);
      scp[r][q][s] = acc;
    }
    __syncthreads();
    // softmax over S=10 (computed redundantly by all 4 quarter-threads of the row)
    float w_att[kS];
    {
      float sc[kS];
#pragma unroll
      for (int s = 0; s < kS; ++s)
        sc[s] = scp[r][0][s] + scp[r][1][s] + scp[r][2][s] + scp[r][3][s];
      float m = sc[0];
#pragma unroll
      for (int s = 1; s < kS; ++s) m = fmaxf(m, sc[s]);
      float sum = 0.f;
#pragma unroll
      for (int s = 0; s < kS; ++s) { w_att[s] = __expf(sc[s] - m); sum += w_att[s]; }
      const float inv = 1.f / sum;
#pragma unroll
      for (int s = 0; s < kS; ++s) w_att[s] *= inv;
    }
    // ctx (own 25 dims) -> xc[64..163]
#pragma unroll
    for (int j = 0; j < DQ; ++j) {
      float acc = 0.f;
      const __hip_bfloat16* er = encb + ((blk * kS) * kH + d0 + j) * BT + r;
#pragma unroll
      for (int s = 0; s < kS; ++s) acc = fmaf(__bfloat162float(er[s * kH * BT]), w_att[s], acc);
      xc[r][kE + d0 + j] = __float2bfloat16(acc);
    }
    __syncthreads();

    // GRU cell, K = 164 (x|ctx) + 100 (h)
    float ar[DQ], az[DQ], anx[DQ], anh[DQ];
#pragma unroll
    for (int j = 0; j < DQ; ++j) {
      ar[j] = bd[d0 + j]; az[j] = bd[kH + d0 + j];
      anx[j] = bd[2 * kH + d0 + j]; anh[j] = bd[3 * kH + d0 + j];
    }
    for (int k = 0; k < KX_D; ++k) {
      const float xv = __bfloat162float(xc[r][k]);
      const float* w = WihT_d + k * G3 + d0;
#pragma unroll
      for (int j = 0; j < DQ; ++j) {
        ar[j]  = fmaf(w[j], xv, ar[j]);
        az[j]  = fmaf(w[kH + j], xv, az[j]);
        anx[j] = fmaf(w[2 * kH + j], xv, anx[j]);
      }
    }
    for (int k = 0; k < kH; ++k) {
      const float hv = h_lds[r][k];
      const float* w = WhhT_d + k * G3 + d0;
#pragma unroll
      for (int j = 0; j < DQ; ++j) {
        ar[j]  = fmaf(w[j], hv, ar[j]);
        az[j]  = fmaf(w[kH + j], hv, az[j]);
        anh[j] = fmaf(w[2 * kH + j], hv, anh[j]);
      }
    }
    float hn[DQ];
#pragma unroll
    for (int j = 0; j < DQ; ++j) {
      const float rg = sigm(ar[j]);
      const float zg = sigm(az[j]);
      const float ng = tanh_(anx[j] + rg * anh[j]);
      hn[j] = (1.f - zg) * ng + zg * h_lds[r][d0 + j];
    }
    __syncthreads();
#pragma unroll
    for (int j = 0; j < DQ; ++j) h_lds[r][d0 + j] = hn[j];
    __syncthreads();

    // logits for this step: quarters cover vocab 7/7/7/6
    const int v0 = (q < 3) ? q * 7 : 21;
    const int nv = (q < 3) ? 7 : 6;
    float av[7];
#pragma unroll
    for (int vi = 0; vi < 7; ++vi) av[vi] = (vi < nv) ? linb[v0 + vi] : 0.f;
    for (int k = 0; k < kH; ++k) {
      const float hv = h_lds[r][k];
      const float* w = linT + k * kV + v0;
#pragma unroll
      for (int vi = 0; vi < 7; ++vi)
        if (vi < nv) av[vi] = fmaf(w[vi], hv, av[vi]);
    }
#pragma unroll
    for (int vi = 0; vi < 7; ++vi)
      if (vi < nv) out[(b * kS + t) * kV + v0 + vi] = av[vi];
  }
}

extern "C" void kernel_launch(void* const* d_in, const int* in_sizes, int n_in,
                              void* d_out, int out_size, void* d_ws, size_t ws_size,
                              hipStream_t stream) {
  const int*   encX = (const int*)d_in[0];
  const int*   decX = (const int*)d_in[1];
  const float* emb  = (const float*)d_in[2];
  const float* eWih = (const float*)d_in[3];
  const float* eWhh = (const float*)d_in[4];
  const float* ebih = (const float*)d_in[5];
  const float* ebhh = (const float*)d_in[6];
  const float* dWih = (const float*)d_in[7];
  const float* dWhh = (const float*)d_in[8];
  const float* dbih = (const float*)d_in[9];
  const float* dbhh = (const float*)d_in[10];
  const float* attW = (const float*)d_in[11];
  const float* linW = (const float*)d_in[12];
  const float* linb = (const float*)d_in[13];
  float* ws  = (float*)d_ws;
  float* o   = (float*)d_out;

  seq2seq_setup<<<64, 256, 0, stream>>>(eWih, eWhh, ebih, ebhh, dWih, dWhh, dbih, dbhh, linW, ws);
  seq2seq_main<<<kB / BT, 256, 0, stream>>>(encX, decX, emb, attW, linb, ws, o);
}

// Round 3
// 1122.405 us; speedup vs baseline: 5.5288x; 5.5288x over previous
//
#include <hip/hip_runtime.h>
#include <hip/hip_bf16.h>

typedef short s16x8 __attribute__((ext_vector_type(8)));
typedef float f32x4 __attribute__((ext_vector_type(4)));
typedef unsigned short ushort_t;
typedef unsigned int uint;

#define DEV static __device__ __forceinline__

namespace {
constexpr int kV = 27, kE = 64, kH = 100, kS = 10, kB = 32768;
constexpr int BT = 64, NB = kB / BT;          // 512 blocks
constexpr int SA = 264;                        // A_lds row stride (bf16 elems)
constexpr int SG = 114;                        // g_lds row stride
constexpr int SS = 45;                         // scp row stride (f32)

// ws layout (ushort offsets). encb FIRST so tiny tail-overruns land in blobs.
constexpr size_t OFF_ENCB   = 0;                               // [NB][10][64][100] bf16
constexpr size_t ENCB_SZ    = (size_t)NB * kS * BT * kH;       // 32,768,000
constexpr size_t OFF_BE_RZ  = ENCB_SZ;                          // [224][160]
constexpr size_t OFF_BE_NH  = OFF_BE_RZ + (size_t)224 * 160;    // [112][128] hi
constexpr size_t OFF_BE_NHL = OFF_BE_NH + (size_t)112 * 128;    // [112][128] lo
constexpr size_t OFF_BE_NX  = OFF_BE_NHL + (size_t)112 * 128;   // [112][32] hi
constexpr size_t OFF_BE_NXL = OFF_BE_NX + (size_t)112 * 32;     // [112][32] lo
constexpr size_t OFF_BD_RZ  = OFF_BE_NXL + (size_t)112 * 32;    // [224][256]
constexpr size_t OFF_BD_NC  = OFF_BD_RZ + (size_t)224 * 256;    // [112][160] hi
constexpr size_t OFF_BD_NCL = OFF_BD_NC + (size_t)112 * 160;    // [112][160] lo
constexpr size_t OFF_BD_NH  = OFF_BD_NCL + (size_t)112 * 160;   // [112][128] hi
constexpr size_t OFF_BD_NHL = OFF_BD_NH + (size_t)112 * 128;    // [112][128] lo
constexpr size_t OFF_WATT   = OFF_BD_NHL + (size_t)112 * 128;   // [112][128]
constexpr size_t OFF_BLIN   = OFF_WATT + (size_t)112 * 128;     // [32][160] hi
constexpr size_t OFF_BLINL  = OFF_BLIN + (size_t)32 * 160;      // [32][160] lo
} // namespace

DEV float sigm(float x) { return 1.f / (1.f + __expf(-x)); }
DEV float tanh_(float x) {
  const float ax = fabsf(x), t = __expf(-2.f * ax);
  return copysignf((1.f - t) / (1.f + t), x);
}
DEV ushort_t f2b(float f) { return __builtin_bit_cast(ushort_t, __float2bfloat16(f)); }
DEV float b2f(ushort_t u) { return __builtin_bit_cast(float, (uint)u << 16); }
DEV float lo16(uint u) { return __builtin_bit_cast(float, u << 16); }
DEV float hi16(uint u) { return __builtin_bit_cast(float, u & 0xFFFF0000u); }
DEV f32x4 MF(s16x8 a, s16x8 b, f32x4 c) {
  return __builtin_amdgcn_mfma_f32_16x16x32_bf16(a, b, c, 0, 0, 0);
}
DEV s16x8 ldB(const ushort_t* W, int KS, int colBase, int rowBase, int lane) {
  const int col = colBase + (lane & 15);
  const int rw  = rowBase + ((lane >> 4) << 3);
  return __builtin_bit_cast(s16x8, *(const uint4*)(W + (size_t)col * KS + rw));
}
DEV s16x8 ldA(const ushort_t* A, int rt, int kf, int lane) {
  const int row = rt * 16 + (lane & 15);
  const int k   = kf * 32 + ((lane >> 4) << 3);
  return __builtin_bit_cast(s16x8, *(const uint4*)(A + row * SA + k));
}
DEV float dot64(const float* __restrict__ a, const float* __restrict__ b) {
  float s = 0.f;
#pragma unroll 16
  for (int k = 0; k < 64; ++k) s += a[k] * b[k];
  return s;
}
DEV void storeHL(ushort_t* ws, size_t offH, size_t offL, int e, float v) {
  const ushort_t h = f2b(v);
  ws[offH + e] = h;
  ws[offL + e] = f2b(v - b2f(h));
}

// ============ setup: bake all weights/tables/biases into bf16 B-blobs ============
__global__ void seq2seq_setup(const float* __restrict__ emb,
    const float* __restrict__ eWih, const float* __restrict__ eWhh,
    const float* __restrict__ ebih, const float* __restrict__ ebhh,
    const float* __restrict__ dWih, const float* __restrict__ dWhh,
    const float* __restrict__ dbih, const float* __restrict__ dbhh,
    const float* __restrict__ attnW, const float* __restrict__ linW,
    const float* __restrict__ linb, ushort_t* __restrict__ ws) {
  const int t0 = blockIdx.x * blockDim.x + threadIdx.x;
  const int stp = gridDim.x * blockDim.x;

  // BE_RZ [224][160]: A_enc = [h 0..99 | pad | onehot 128..159]; bias at oh-slot 27 (k=155)
  for (int e = t0; e < 224 * 160; e += stp) {
    int col = e / 160, k = e - col * 160;
    int g = col < 112 ? 0 : 1, d = col - g * 112;
    float v = 0.f;
    if (d < 100) {
      int wr = g * 100 + d;
      if (k < 100) v = eWhh[wr * 100 + k];
      else if (k >= 128 && k < 155) v = dot64(emb + (k - 128) * 64, eWih + (size_t)wr * 64);
      else if (k == 155) v = ebih[wr] + ebhh[wr];
    }
    ws[OFF_BE_RZ + e] = f2b(v);
  }
  // BE_NH [112][128] hi/lo: h-part of n + bhh_n at const-col k==100
  for (int e = t0; e < 112 * 128; e += stp) {
    int col = e / 128, k = e - col * 128;
    float v = 0.f;
    if (col < 100) {
      int wr = 200 + col;
      if (k < 100) v = eWhh[wr * 100 + k];
      else if (k == 100) v = ebhh[wr];
    }
    storeHL(ws, OFF_BE_NH, OFF_BE_NHL, e, v);
  }
  // BE_NX [112][32] hi/lo: x-table of n + bih_n at oh-slot 27
  for (int e = t0; e < 112 * 32; e += stp) {
    int col = e / 32, k = e - col * 32;
    float v = 0.f;
    if (col < 100) {
      int wr = 200 + col;
      if (k < 27) v = dot64(emb + k * 64, eWih + (size_t)wr * 64);
      else if (k == 27) v = ebih[wr];
    }
    storeHL(ws, OFF_BE_NX, OFF_BE_NXL, e, v);
  }
  // BD_RZ [224][256]: A_dec = [ctx 0..99 | pad | h 112..211 | 1@212 | pad | onehot 224..255]
  for (int e = t0; e < 224 * 256; e += stp) {
    int col = e / 256, k = e - col * 256;
    int g = col < 112 ? 0 : 1, d = col - g * 112;
    float v = 0.f;
    if (d < 100) {
      int wr = g * 100 + d;
      if (k < 100) v = dWih[(size_t)wr * 164 + 64 + k];
      else if (k >= 112 && k < 212) v = dWhh[wr * 100 + (k - 112)];
      else if (k >= 224 && k < 251) v = dot64(emb + (k - 224) * 64, dWih + (size_t)wr * 164);
      else if (k == 251) v = dbih[wr] + dbhh[wr];
    }
    ws[OFF_BD_RZ + e] = f2b(v);
  }
  // BD_NC [112][160] hi/lo: ctx-part of n (k<100) + x-table (128..154) + bih_n (155)
  for (int e = t0; e < 112 * 160; e += stp) {
    int col = e / 160, k = e - col * 160;
    float v = 0.f;
    if (col < 100) {
      int wr = 200 + col;
      if (k < 100) v = dWih[(size_t)wr * 164 + 64 + k];
      else if (k >= 128 && k < 155) v = dot64(emb + (k - 128) * 64, dWih + (size_t)wr * 164);
      else if (k == 155) v = dbih[wr];
    }
    storeHL(ws, OFF_BD_NC, OFF_BD_NCL, e, v);
  }
  // BD_NH [112][128] hi/lo: rows = A_k-96; h at 16..115; bhh_n at 116 (A col 212)
  for (int e = t0; e < 112 * 128; e += stp) {
    int col = e / 128, k = e - col * 128;
    float v = 0.f;
    if (col < 100) {
      int wr = 200 + col;
      if (k >= 16 && k < 116) v = dWhh[wr * 100 + (k - 16)];
      else if (k == 116) v = dbhh[wr];
    }
    storeHL(ws, OFF_BD_NH, OFF_BD_NHL, e, v);
  }
  // WATT [112][128]: g[d'] = sum_h h*attnW[h][d']; rows = A_k-96 (h at 16..115)
  for (int e = t0; e < 112 * 128; e += stp) {
    int col = e / 128, k = e - col * 128;
    float v = 0.f;
    if (col < 100 && k >= 16 && k < 116) v = attnW[(k - 16) * 100 + col];
    ws[OFF_WATT + e] = f2b(v);
  }
  // BLIN [32][160] hi/lo: linW rows 16..115 (h); linb at 155 (oh-slot 27)
  for (int e = t0; e < 32 * 160; e += stp) {
    int col = e / 160, k = e - col * 160;
    float v = 0.f;
    if (col < 27) {
      if (k >= 16 && k < 116) v = linW[col * 100 + (k - 16)];
      else if (k == 155) v = linb[col];
    }
    storeHL(ws, OFF_BLIN, OFF_BLINL, e, v);
  }
}

// ============ fused main kernel ============
__global__ __launch_bounds__(256, 2)
void seq2seq_main(const int* __restrict__ encX, const int* __restrict__ decX,
                  ushort_t* __restrict__ ws, float* __restrict__ out) {
  const int tid  = threadIdx.x;
  const int lane = tid & 63;
  const int w    = __builtin_amdgcn_readfirstlane(tid >> 6);
  const int blk  = blockIdx.x;
  const int b0   = blk * BT;
  const int cl   = lane & 15;
  const int g4   = lane >> 4;

  __shared__ alignas(16) ushort_t Ash[BT * SA];
  __shared__ alignas(16) ushort_t Gsh[BT * SG];
  __shared__ alignas(16) float    Ssh[BT * SS];

  ushort_t* encb = ws + OFF_ENCB;
  const ushort_t* BE_RZ  = ws + OFF_BE_RZ;
  const ushort_t* BE_NH  = ws + OFF_BE_NH;
  const ushort_t* BE_NHL = ws + OFF_BE_NHL;
  const ushort_t* BE_NX  = ws + OFF_BE_NX;
  const ushort_t* BE_NXL = ws + OFF_BE_NXL;
  const ushort_t* BD_RZ  = ws + OFF_BD_RZ;
  const ushort_t* BD_NC  = ws + OFF_BD_NC;
  const ushort_t* BD_NCL = ws + OFF_BD_NCL;
  const ushort_t* BD_NH  = ws + OFF_BD_NH;
  const ushort_t* BD_NHL = ws + OFF_BD_NHL;
  const ushort_t* WATT   = ws + OFF_WATT;
  const ushort_t* BLIN   = ws + OFF_BLIN;
  const ushort_t* BLINL  = ws + OFF_BLINL;

  const int c0 = w, c1 = (w < 3) ? w + 4 : -1;
  float hreg[2][4][4];
#pragma unroll
  for (int cc = 0; cc < 2; ++cc)
#pragma unroll
    for (int rt = 0; rt < 4; ++rt)
#pragma unroll
      for (int i = 0; i < 4; ++i) hreg[cc][rt][i] = 0.f;

  auto onehot = [&](const int* X, int tt, int base) {
    const int row = tid & 63, q8 = (tid >> 6) * 8;
    const int tok = X[(b0 + row) * kS + tt];
    uint pk[4];
#pragma unroll
    for (int p = 0; p < 4; ++p) {
      const int j0 = q8 + p * 2;
      const uint lo = (j0 == tok || j0 == 27) ? 0x3F80u : 0u;
      const uint hi = (j0 + 1 == tok || j0 + 1 == 27) ? 0x3F80u : 0u;
      pk[p] = lo | (hi << 16);
    }
    *(uint4*)&Ash[row * SA + base + q8] = make_uint4(pk[0], pk[1], pk[2], pk[3]);
  };

  // ---- init: blanket-zero A (kills uninit-LDS NaN), const-1 cols, enc onehot t=0 ----
  for (int i = tid; i < BT * SA / 2; i += 256) ((uint*)Ash)[i] = 0u;
  __syncthreads();
  if (tid < 64) {
    Ash[tid * SA + 100] = 0x3F80;   // encoder bhh_n selector
    Ash[tid * SA + 212] = 0x3F80;   // decoder bhh_n selector
  }
  onehot(encX, 0, 128);
  __syncthreads();

  // ================= encoder =================
  for (int t = 0; t < kS; ++t) {
    f32x4 aR[2][4], aZ[2][4], aNH[2][4], aNX[2][4];
#pragma unroll
    for (int cc = 0; cc < 2; ++cc)
#pragma unroll
      for (int rt = 0; rt < 4; ++rt) { aR[cc][rt] = f32x4{0,0,0,0}; aZ[cc][rt] = f32x4{0,0,0,0}; aNH[cc][rt] = f32x4{0,0,0,0}; aNX[cc][rt] = f32x4{0,0,0,0}; }
#pragma unroll
    for (int kf = 0; kf < 5; ++kf) {
      s16x8 a[4];
#pragma unroll
      for (int rt = 0; rt < 4; ++rt) a[rt] = ldA(Ash, rt, kf, lane);
#pragma unroll
      for (int cc = 0; cc < 2; ++cc) {
        const int c = cc ? c1 : c0;
        if (c >= 0) {
          s16x8 br = ldB(BE_RZ, 160, 16 * c, kf * 32, lane);
          s16x8 bz = ldB(BE_RZ, 160, 112 + 16 * c, kf * 32, lane);
          s16x8 bn = (kf < 4) ? ldB(BE_NH, 128, 16 * c, kf * 32, lane)
                              : ldB(BE_NX, 32, 16 * c, 0, lane);
          s16x8 bl = (kf < 4) ? ldB(BE_NHL, 128, 16 * c, kf * 32, lane)
                              : ldB(BE_NXL, 32, 16 * c, 0, lane);
#pragma unroll
          for (int rt = 0; rt < 4; ++rt) {
            aR[cc][rt] = MF(a[rt], br, aR[cc][rt]);
            aZ[cc][rt] = MF(a[rt], bz, aZ[cc][rt]);
            if (kf < 4) { aNH[cc][rt] = MF(a[rt], bn, aNH[cc][rt]); aNH[cc][rt] = MF(a[rt], bl, aNH[cc][rt]); }
            else        { aNX[cc][rt] = MF(a[rt], bn, aNX[cc][rt]); aNX[cc][rt] = MF(a[rt], bl, aNX[cc][rt]); }
          }
        }
      }
    }
#pragma unroll
    for (int cc = 0; cc < 2; ++cc) {
      const int c = cc ? c1 : c0;
      if (c >= 0) {
#pragma unroll
        for (int rt = 0; rt < 4; ++rt)
#pragma unroll
          for (int i = 0; i < 4; ++i) {
            const float r = sigm(aR[cc][rt][i]);
            const float z = sigm(aZ[cc][rt][i]);
            const float n = tanh_(aNX[cc][rt][i] + r * aNH[cc][rt][i]);
            hreg[cc][rt][i] = (1.f - z) * n + z * hreg[cc][rt][i];
          }
      }
    }
    __syncthreads();
    // writes: h -> A + encb; onehot(t+1) / decoder init
#pragma unroll
    for (int cc = 0; cc < 2; ++cc) {
      const int c = cc ? c1 : c0;
      if (c >= 0) {
        const int d = 16 * c + cl;
        if (d < 100) {
#pragma unroll
          for (int rt = 0; rt < 4; ++rt)
#pragma unroll
            for (int i = 0; i < 4; ++i) {
              const int row = rt * 16 + g4 * 4 + i;
              const ushort_t us = f2b(hreg[cc][rt][i]);
              Ash[row * SA + d] = us;
              encb[((size_t)(blk * kS + t) * BT + row) * kH + d] = us;
            }
        }
      }
    }
    if (t < kS - 1) onehot(encX, t + 1, 128);
    else {
#pragma unroll
      for (int cc = 0; cc < 2; ++cc) {
        const int c = cc ? c1 : c0;
        if (c >= 0) {
          const int d = 16 * c + cl;
          if (d < 100)
#pragma unroll
            for (int rt = 0; rt < 4; ++rt)
#pragma unroll
              for (int i = 0; i < 4; ++i)
                Ash[(rt * 16 + g4 * 4 + i) * SA + 112 + d] = f2b(hreg[cc][rt][i]);
        }
      }
      onehot(decX, 0, 224);
    }
    __syncthreads();
  }

  // ================= decoder =================
  const int r_  = tid & 63;
  const int dq0 = (tid >> 6) * 26;
  for (int t = 0; t < kS; ++t) {
    // ---- ph1: g = h @ attnW -> Gsh ----
#pragma unroll
    for (int cc = 0; cc < 2; ++cc) {
      const int c = cc ? c1 : c0;
      if (c >= 0) {
        f32x4 aG[4] = {f32x4{0,0,0,0}, f32x4{0,0,0,0}, f32x4{0,0,0,0}, f32x4{0,0,0,0}};
#pragma unroll
        for (int kf = 3; kf < 7; ++kf) {
          s16x8 bg = ldB(WATT, 128, 16 * c, (kf - 3) * 32, lane);
#pragma unroll
          for (int rt = 0; rt < 4; ++rt) aG[rt] = MF(ldA(Ash, rt, kf, lane), bg, aG[rt]);
        }
        const int d = 16 * c + cl;
        if (d < 112)
#pragma unroll
          for (int rt = 0; rt < 4; ++rt)
#pragma unroll
            for (int i = 0; i < 4; ++i)
              Gsh[(rt * 16 + g4 * 4 + i) * SG + d] = f2b(aG[rt][i]);
      }
    }
    __syncthreads();
    // ---- ph2: scores ----
    {
      float gs[26];
#pragma unroll
      for (int j = 0; j < 13; ++j) {
        const uint u = *(const uint*)&Gsh[r_ * SG + dq0 + 2 * j];
        gs[2 * j] = lo16(u); gs[2 * j + 1] = hi16(u);
      }
#pragma unroll
      for (int s = 0; s < kS; ++s) {
        const ushort_t* ep = encb + ((size_t)(blk * kS + s) * BT + r_) * kH + dq0;
        float acc = 0.f;
#pragma unroll
        for (int j = 0; j < 13; ++j) {
          const uint u = *(const uint*)(ep + 2 * j);
          acc += lo16(u) * gs[2 * j] + hi16(u) * gs[2 * j + 1];
        }
        Ssh[r_ * SS + (tid >> 6) * 11 + s] = acc;
      }
    }
    __syncthreads();
    // ---- ph3: softmax + ctx -> A[0..99] ----
    {
      float sc[kS], wat[kS];
#pragma unroll
      for (int s = 0; s < kS; ++s)
        sc[s] = Ssh[r_ * SS + s] + Ssh[r_ * SS + 11 + s] + Ssh[r_ * SS + 22 + s] + Ssh[r_ * SS + 33 + s];
      float m = sc[0];
#pragma unroll
      for (int s = 1; s < kS; ++s) m = fmaxf(m, sc[s]);
      float sum = 0.f;
#pragma unroll
      for (int s = 0; s < kS; ++s) { wat[s] = __expf(sc[s] - m); sum += wat[s]; }
      const float inv = 1.f / sum;
#pragma unroll
      for (int s = 0; s < kS; ++s) wat[s] *= inv;
#pragma unroll
      for (int j = 0; j < 13; ++j) {
        if (dq0 + 2 * j + 1 < 100) {
          float v0 = 0.f, v1 = 0.f;
#pragma unroll
          for (int s = 0; s < kS; ++s) {
            const uint u = *(const uint*)(encb + ((size_t)(blk * kS + s) * BT + r_) * kH + dq0 + 2 * j);
            v0 += wat[s] * lo16(u); v1 += wat[s] * hi16(u);
          }
          *(uint*)&Ash[r_ * SA + dq0 + 2 * j] = (uint)f2b(v0) | ((uint)f2b(v1) << 16);
        }
      }
    }
    __syncthreads();
    // ---- ph4: GRU GEMMs + nonlin ----
    {
      f32x4 aR[2][4], aZ[2][4], aNC[2][4], aNH[2][4];
#pragma unroll
      for (int cc = 0; cc < 2; ++cc)
#pragma unroll
        for (int rt = 0; rt < 4; ++rt) { aR[cc][rt] = f32x4{0,0,0,0}; aZ[cc][rt] = f32x4{0,0,0,0}; aNC[cc][rt] = f32x4{0,0,0,0}; aNH[cc][rt] = f32x4{0,0,0,0}; }
#pragma unroll
      for (int kf = 0; kf < 8; ++kf) {
        s16x8 a[4];
#pragma unroll
        for (int rt = 0; rt < 4; ++rt) a[rt] = ldA(Ash, rt, kf, lane);
#pragma unroll
        for (int cc = 0; cc < 2; ++cc) {
          const int c = cc ? c1 : c0;
          if (c >= 0) {
            s16x8 br = ldB(BD_RZ, 256, 16 * c, kf * 32, lane);
            s16x8 bz = ldB(BD_RZ, 256, 112 + 16 * c, kf * 32, lane);
#pragma unroll
            for (int rt = 0; rt < 4; ++rt) {
              aR[cc][rt] = MF(a[rt], br, aR[cc][rt]);
              aZ[cc][rt] = MF(a[rt], bz, aZ[cc][rt]);
            }
            if (kf < 4 || kf == 7) {
              const int rb = (kf < 4) ? kf * 32 : 128;
              s16x8 bnc = ldB(BD_NC, 160, 16 * c, rb, lane);
              s16x8 bncl = ldB(BD_NCL, 160, 16 * c, rb, lane);
#pragma unroll
              for (int rt = 0; rt < 4; ++rt) {
                aNC[cc][rt] = MF(a[rt], bnc, aNC[cc][rt]);
                aNC[cc][rt] = MF(a[rt], bncl, aNC[cc][rt]);
              }
            }
            if (kf >= 3 && kf <= 6) {
              s16x8 bnh = ldB(BD_NH, 128, 16 * c, (kf - 3) * 32, lane);
              s16x8 bnhl = ldB(BD_NHL, 128, 16 * c, (kf - 3) * 32, lane);
#pragma unroll
              for (int rt = 0; rt < 4; ++rt) {
                aNH[cc][rt] = MF(a[rt], bnh, aNH[cc][rt]);
                aNH[cc][rt] = MF(a[rt], bnhl, aNH[cc][rt]);
              }
            }
          }
        }
      }
#pragma unroll
      for (int cc = 0; cc < 2; ++cc) {
        const int c = cc ? c1 : c0;
        if (c >= 0) {
#pragma unroll
          for (int rt = 0; rt < 4; ++rt)
#pragma unroll
            for (int i = 0; i < 4; ++i) {
              const float r = sigm(aR[cc][rt][i]);
              const float z = sigm(aZ[cc][rt][i]);
              const float n = tanh_(aNC[cc][rt][i] + r * aNH[cc][rt][i]);
              hreg[cc][rt][i] = (1.f - z) * n + z * hreg[cc][rt][i];
            }
        }
      }
    }
    __syncthreads();
    // ---- ph5: h write + next onehot ----
#pragma unroll
    for (int cc = 0; cc < 2; ++cc) {
      const int c = cc ? c1 : c0;
      if (c >= 0) {
        const int d = 16 * c + cl;
        if (d < 100)
#pragma unroll
          for (int rt = 0; rt < 4; ++rt)
#pragma unroll
            for (int i = 0; i < 4; ++i)
              Ash[(rt * 16 + g4 * 4 + i) * SA + 112 + d] = f2b(hreg[cc][rt][i]);
      }
    }
    if (t < kS - 1) onehot(decX, t + 1, 224);
    __syncthreads();
    // ---- ph6: logits (wave w -> its 16 rows) ----
    {
      f32x4 aL[2] = {f32x4{0,0,0,0}, f32x4{0,0,0,0}};
#pragma unroll
      for (int kf = 3; kf < 8; ++kf) {
        s16x8 a = ldA(Ash, w, kf, lane);
        const int rb = (kf < 7) ? (kf - 3) * 32 : 128;
#pragma unroll
        for (int ct = 0; ct < 2; ++ct) {
          s16x8 bl = ldB(BLIN, 160, 16 * ct, rb, lane);
          s16x8 bll = ldB(BLINL, 160, 16 * ct, rb, lane);
          aL[ct] = MF(a, bl, aL[ct]);
          aL[ct] = MF(a, bll, aL[ct]);
        }
      }
#pragma unroll
      for (int ct = 0; ct < 2; ++ct) {
        const int v = 16 * ct + cl;
        if (v < kV)
#pragma unroll
          for (int i = 0; i < 4; ++i) {
            const int row = w * 16 + g4 * 4 + i;
            out[((size_t)(b0 + row) * kS + t) * kV + v] = aL[ct][i];
          }
      }
    }
  }
}

extern "C" void kernel_launch(void* const* d_in, const int* in_sizes, int n_in,
                              void* d_out, int out_size, void* d_ws, size_t ws_size,
                              hipStream_t stream) {
  const int*   encX = (const int*)d_in[0];
  const int*   decX = (const int*)d_in[1];
  const float* emb  = (const float*)d_in[2];
  const float* eWih = (const float*)d_in[3];
  const float* eWhh = (const float*)d_in[4];
  const float* ebih = (const float*)d_in[5];
  const float* ebhh = (const float*)d_in[6];
  const float* dWih = (const float*)d_in[7];
  const float* dWhh = (const float*)d_in[8];
  const float* dbih = (const float*)d_in[9];
  const float* dbhh = (const float*)d_in[10];
  const float* attW = (const float*)d_in[11];
  const float* linW = (const float*)d_in[12];
  const float* linb = (const float*)d_in[13];
  ushort_t* ws = (ushort_t*)d_ws;
  float* o = (float*)d_out;

  seq2seq_setup<<<512, 256, 0, stream>>>(emb, eWih, eWhh, ebih, ebhh,
                                         dWih, dWhh, dbih, dbhh, attW, linW, linb, ws);
  seq2seq_main<<<NB, 256, 0, stream>>>(encX, decX, ws, o);
}

// Round 4
// 1050.212 us; speedup vs baseline: 5.9089x; 1.0687x over previous
//
#include <hip/hip_runtime.h>
#include <hip/hip_bf16.h>

typedef short s16x8 __attribute__((ext_vector_type(8)));
typedef float f32x4 __attribute__((ext_vector_type(4)));
typedef unsigned short ushort_t;
typedef unsigned int uint;

#define DEV static __device__ __forceinline__

namespace {
constexpr int kV = 27, kS = 10, kB = 32768;
constexpr int BT = 64, NB = kB / BT;   // 512 blocks

// blob offsets (ushort units), all fragment-ordered: [(tile*nF+fi)*512 + lane*8 + e]
constexpr size_t O_BE_R   = 0;
constexpr size_t O_BE_Z   = O_BE_R   + (size_t)7*4*512;
constexpr size_t O_BE_NH  = O_BE_Z   + (size_t)7*4*512;
constexpr size_t O_BE_NHL = O_BE_NH  + (size_t)7*4*512;
constexpr size_t O_BE_NX  = O_BE_NHL + (size_t)7*4*512;
constexpr size_t O_BE_NXL = O_BE_NX  + (size_t)7*1*512;
constexpr size_t O_BD_R   = O_BE_NXL + (size_t)7*1*512;
constexpr size_t O_BD_Z   = O_BD_R   + (size_t)7*8*512;
constexpr size_t O_BD_NC  = O_BD_Z   + (size_t)7*8*512;
constexpr size_t O_BD_NCL = O_BD_NC  + (size_t)7*6*512;
constexpr size_t O_BD_NH  = O_BD_NCL + (size_t)7*6*512;
constexpr size_t O_BD_NHL = O_BD_NH  + (size_t)7*5*512;
constexpr size_t O_WATT   = O_BD_NHL + (size_t)7*5*512;
constexpr size_t O_BLIN   = O_WATT   + (size_t)7*4*512;
constexpr size_t O_BLINL  = O_BLIN   + (size_t)2*5*512;
} // namespace

DEV float sigm(float x) { return 1.f / (1.f + __expf(-x)); }
DEV float tanh_(float x) {
  const float ax = fabsf(x), t = __expf(-2.f * ax);
  return copysignf((1.f - t) / (1.f + t), x);
}
DEV ushort_t f2b(float f) { return __builtin_bit_cast(ushort_t, __float2bfloat16(f)); }
DEV float b2f(ushort_t u) { return __builtin_bit_cast(float, (uint)u << 16); }
DEV float lo16(uint u) { return __builtin_bit_cast(float, u << 16); }
DEV float hi16(uint u) { return __builtin_bit_cast(float, u & 0xFFFF0000u); }
DEV f32x4 MF(s16x8 a, s16x8 b, f32x4 c) {
  return __builtin_amdgcn_mfma_f32_16x16x32_bf16(a, b, c, 0, 0, 0);
}
DEV float dot64(const float* __restrict__ a, const float* __restrict__ b) {
  float s = 0.f;
#pragma unroll 16
  for (int k = 0; k < 64; ++k) s += a[k] * b[k];
  return s;
}
DEV void storeHL(ushort_t* ws, size_t offH, size_t offL, int e, float v) {
  const ushort_t h = f2b(v);
  ws[offH + e] = h;
  ws[offL + e] = f2b(v - b2f(h));
}

// fragment-ordered B load: one coalesced 1KB block per (tile,frag)
DEV s16x8 ldBF(const ushort_t* p, int fragIdx, int lane) {
  return __builtin_bit_cast(s16x8, *(const uint4*)(p + ((size_t)fragIdx << 9) + (lane << 3)));
}
// swizzled A-tile (row stride 512B, XOR (row&7)<<4 kills 16-way bank conflicts)
DEV uint swzb(int row, int byteoff) { return (uint)((row * 512 + byteoff) ^ ((row & 7) << 4)); }
DEV s16x8 ldA(const ushort_t* A, int rt, int kf, int cl, int g4) {
  const int row = rt * 16 + cl;
  return __builtin_bit_cast(s16x8, *(const uint4*)((const char*)A + swzb(row, kf * 64 + g4 * 16)));
}
DEV void stA16(ushort_t* A, int row, int col, ushort_t v) {
  *(ushort_t*)((char*)A + swzb(row, col * 2)) = v;
}
DEV void stA32(ushort_t* A, int row, int byteoff, uint v) {
  *(uint*)((char*)A + swzb(row, byteoff)) = v;
}
DEV uint2 ldA64(const ushort_t* A, int row, int byteoff) {
  return *(const uint2*)((const char*)A + swzb(row, byteoff));
}

// ============ setup: bake fragment-ordered bf16 blobs ============
// Encoder A (K=128): [h 0..99 | oh 100..126 | const1 @127]
// Decoder A (K=256): [ctx 0..99 | h 100..199 | oh 200..226 | const1 @227 | pad 0]
__global__ void seq2seq_setup(const float* __restrict__ emb,
    const float* __restrict__ eWih, const float* __restrict__ eWhh,
    const float* __restrict__ ebih, const float* __restrict__ ebhh,
    const float* __restrict__ dWih, const float* __restrict__ dWhh,
    const float* __restrict__ dbih, const float* __restrict__ dbhh,
    const float* __restrict__ attnW, const float* __restrict__ linW,
    const float* __restrict__ linb, ushort_t* __restrict__ ws) {
  const int t0 = blockIdx.x * blockDim.x + threadIdx.x;
  const int stp = gridDim.x * blockDim.x;

  // BE_R / BE_Z / BE_NH(hi,lo): 7 tiles x frags 0..3
  for (int e = t0; e < 7 * 4 * 512; e += stp) {
    int c = e >> 11, rem = e & 2047, fi = rem >> 9, l = (rem >> 3) & 63, i8 = rem & 7;
    int d = 16 * c + (l & 15);
    int k = fi * 32 + ((l >> 4) << 3) + i8;
    float vr = 0, vz = 0, vnh = 0;
    if (d < 100) {
      if (k < 100) { vr = eWhh[d*100+k]; vz = eWhh[(100+d)*100+k]; vnh = eWhh[(200+d)*100+k]; }
      else if (k < 127) {
        int tok = k - 100;
        vr = dot64(emb + tok*64, eWih + (size_t)d*64);
        vz = dot64(emb + tok*64, eWih + (size_t)(100+d)*64);
      } else { // k == 127 (const-1)
        vr = ebih[d] + ebhh[d]; vz = ebih[100+d] + ebhh[100+d]; vnh = ebhh[200+d];
      }
    }
    ws[O_BE_R + e] = f2b(vr);
    ws[O_BE_Z + e] = f2b(vz);
    storeHL(ws, O_BE_NH, O_BE_NHL, e, vnh);
  }
  // BE_NX(hi,lo): 7 tiles x frag {3} (rows 96..127)
  for (int e = t0; e < 7 * 512; e += stp) {
    int c = e >> 9, l = (e >> 3) & 63, i8 = e & 7;
    int d = 16 * c + (l & 15);
    int k = 96 + ((l >> 4) << 3) + i8;
    float v = 0;
    if (d < 100) {
      if (k >= 100 && k < 127) v = dot64(emb + (k-100)*64, eWih + (size_t)(200+d)*64);
      else if (k == 127) v = ebih[200+d];
    }
    storeHL(ws, O_BE_NX, O_BE_NXL, e, v);
  }
  // BD_R / BD_Z: 7 tiles x frags 0..7
  for (int e = t0; e < 7 * 8 * 512; e += stp) {
    int c = e >> 12, rem = e & 4095, fi = rem >> 9, l = (rem >> 3) & 63, i8 = rem & 7;
    int d = 16 * c + (l & 15);
    int k = fi * 32 + ((l >> 4) << 3) + i8;
    float vr = 0, vz = 0;
    if (d < 100) {
      int wr = d, wz = 100 + d;
      if (k < 100)       { vr = dWih[(size_t)wr*164+64+k];        vz = dWih[(size_t)wz*164+64+k]; }
      else if (k < 200)  { vr = dWhh[wr*100+k-100];               vz = dWhh[wz*100+k-100]; }
      else if (k < 227)  { vr = dot64(emb+(k-200)*64, dWih+(size_t)wr*164);
                           vz = dot64(emb+(k-200)*64, dWih+(size_t)wz*164); }
      else if (k == 227) { vr = dbih[wr]+dbhh[wr];                vz = dbih[wz]+dbhh[wz]; }
    }
    ws[O_BD_R + e] = f2b(vr);
    ws[O_BD_Z + e] = f2b(vz);
  }
  // BD_NC(hi,lo): 7 tiles x frags {0,1,2,3,6,7}
  for (int e = t0; e < 7 * 6 * 512; e += stp) {
    int c = e / (6*512), rem = e - c*6*512, fi = rem >> 9, l = (rem >> 3) & 63, i8 = rem & 7;
    int fid = (fi < 4) ? fi : fi + 2;
    int d = 16 * c + (l & 15);
    int k = fid * 32 + ((l >> 4) << 3) + i8;
    float v = 0;
    if (d < 100) {
      int wr = 200 + d;
      if (k < 100) v = dWih[(size_t)wr*164+64+k];
      else if (k >= 200 && k < 227) v = dot64(emb+(k-200)*64, dWih+(size_t)wr*164);
      else if (k == 227) v = dbih[wr];
    }
    storeHL(ws, O_BD_NC, O_BD_NCL, e, v);
  }
  // BD_NH(hi,lo): 7 tiles x frags {3,4,5,6,7}
  for (int e = t0; e < 7 * 5 * 512; e += stp) {
    int c = e / (5*512), rem = e - c*5*512, fi = rem >> 9, l = (rem >> 3) & 63, i8 = rem & 7;
    int d = 16 * c + (l & 15);
    int k = (3 + fi) * 32 + ((l >> 4) << 3) + i8;
    float v = 0;
    if (d < 100) {
      int wr = 200 + d;
      if (k >= 100 && k < 200) v = dWhh[wr*100+k-100];
      else if (k == 227) v = dbhh[wr];
    }
    storeHL(ws, O_BD_NH, O_BD_NHL, e, v);
  }
  // WATT: 7 tiles x frags {3,4,5,6}; g[d] = sum_j h[j]*attnW[j][d]
  for (int e = t0; e < 7 * 4 * 512; e += stp) {
    int c = e >> 11, rem = e & 2047, fi = rem >> 9, l = (rem >> 3) & 63, i8 = rem & 7;
    int d = 16 * c + (l & 15);
    int k = (3 + fi) * 32 + ((l >> 4) << 3) + i8;
    float v = 0;
    if (d < 100 && k >= 100 && k < 200) v = attnW[(k-100)*100 + d];
    ws[O_WATT + e] = f2b(v);
  }
  // BLIN(hi,lo): 2 tiles x frags {3,4,5,6,7}
  for (int e = t0; e < 2 * 5 * 512; e += stp) {
    int c = e / (5*512), rem = e - c*5*512, fi = rem >> 9, l = (rem >> 3) & 63, i8 = rem & 7;
    int vv = 16 * c + (l & 15);
    int k = (3 + fi) * 32 + ((l >> 4) << 3) + i8;
    float v = 0;
    if (vv < kV) {
      if (k >= 100 && k < 200) v = linW[vv*100 + k-100];
      else if (k == 227) v = linb[vv];
    }
    storeHL(ws, O_BLIN, O_BLINL, e, v);
  }
}

// ============ fused main kernel: 512 thr = 8 waves (2 row-halves x 4 col-groups) ============
__global__ __launch_bounds__(512, 2)
void seq2seq_main(const int* __restrict__ encX, const int* __restrict__ decX,
                  const ushort_t* __restrict__ ws, float* __restrict__ out) {
  const int tid  = threadIdx.x;
  const int lane = tid & 63;
  const int w    = __builtin_amdgcn_readfirstlane(tid >> 6);
  const int cl   = lane & 15, g4 = lane >> 4;
  const int h2 = w >> 2, g = w & 3;
  const int rt0 = h2 * 2;
  const int c0 = g, c1 = (g < 3) ? 4 + g : -1;
  const int b0 = blockIdx.x * BT;

  __shared__ alignas(16) ushort_t Ash[BT * 256];        // 32,768 B, swizzled
  __shared__ alignas(16) ushort_t Esh[10 * BT * 100];   // 128,000 B enc_out bf16
  __shared__ alignas(16) float    Ssh[BT * 10];         // 2,560 B scores

  const ushort_t* BER   = ws + O_BE_R;
  const ushort_t* BEZ   = ws + O_BE_Z;
  const ushort_t* BENH  = ws + O_BE_NH;
  const ushort_t* BENHL = ws + O_BE_NHL;
  const ushort_t* BENX  = ws + O_BE_NX;
  const ushort_t* BENXL = ws + O_BE_NXL;
  const ushort_t* BDR   = ws + O_BD_R;
  const ushort_t* BDZ   = ws + O_BD_Z;
  const ushort_t* BDNC  = ws + O_BD_NC;
  const ushort_t* BDNCL = ws + O_BD_NCL;
  const ushort_t* BDNH  = ws + O_BD_NH;
  const ushort_t* BDNHL = ws + O_BD_NHL;
  const ushort_t* WATT  = ws + O_WATT;
  const ushort_t* BLIN  = ws + O_BLIN;
  const ushort_t* BLINL = ws + O_BLINL;

  float hreg[2][2][4];
#pragma unroll
  for (int cc = 0; cc < 2; ++cc)
#pragma unroll
    for (int rr = 0; rr < 2; ++rr)
#pragma unroll
      for (int i = 0; i < 4; ++i) hreg[cc][rr][i] = 0.f;

  // waves 0..3 write onehot (8 slots each = slots 0..31; 28..31 are always 0, land in scratch cols)
  auto onehot = [&](const int* X, int tt, int baseByte) {
    if (w < 4) {
      const int row = lane;
      const int tok = X[(b0 + row) * kS + tt];
#pragma unroll
      for (int p = 0; p < 4; ++p) {
        const int j0 = w * 8 + 2 * p;
        const uint lo = (j0 == tok || j0 == 27) ? 0x3F80u : 0u;
        const uint hi = (j0 + 1 == tok || j0 + 1 == 27) ? 0x3F80u : 0u;
        stA32(Ash, row, baseByte + j0 * 2, lo | (hi << 16));
      }
    }
  };

  // init: zero A (finite everywhere), then first onehot
  for (int i = tid; i < BT * 256 / 2; i += 512) ((uint*)Ash)[i] = 0u;
  __syncthreads();
  onehot(encX, 0, 200);
  __syncthreads();

  // ================= encoder =================
  for (int t = 0; t < kS; ++t) {
    f32x4 R[2][2], Zx[2][2], NHa[2][2], NXa[2][2];
#pragma unroll
    for (int cc = 0; cc < 2; ++cc)
#pragma unroll
      for (int rr = 0; rr < 2; ++rr) {
        R[cc][rr] = f32x4{0,0,0,0}; Zx[cc][rr] = f32x4{0,0,0,0};
        NHa[cc][rr] = f32x4{0,0,0,0}; NXa[cc][rr] = f32x4{0,0,0,0};
      }
#pragma unroll
    for (int kf = 0; kf < 4; ++kf) {
      s16x8 a0 = ldA(Ash, rt0, kf, cl, g4);
      s16x8 a1 = ldA(Ash, rt0 + 1, kf, cl, g4);
#pragma unroll
      for (int cc = 0; cc < 2; ++cc) {
        const int c = cc ? c1 : c0;
        if (c < 0) continue;
        s16x8 br  = ldBF(BER,   c * 4 + kf, lane);
        s16x8 bz  = ldBF(BEZ,   c * 4 + kf, lane);
        s16x8 bh  = ldBF(BENH,  c * 4 + kf, lane);
        s16x8 bhl = ldBF(BENHL, c * 4 + kf, lane);
        R[cc][0]  = MF(a0, br, R[cc][0]);   R[cc][1]  = MF(a1, br, R[cc][1]);
        Zx[cc][0] = MF(a0, bz, Zx[cc][0]);  Zx[cc][1] = MF(a1, bz, Zx[cc][1]);
        NHa[cc][0]= MF(a0, bh, NHa[cc][0]); NHa[cc][1]= MF(a1, bh, NHa[cc][1]);
        NHa[cc][0]= MF(a0, bhl,NHa[cc][0]); NHa[cc][1]= MF(a1, bhl,NHa[cc][1]);
        if (kf == 3) {
          s16x8 bx  = ldBF(BENX,  c, lane);
          s16x8 bxl = ldBF(BENXL, c, lane);
          NXa[cc][0] = MF(a0, bx, NXa[cc][0]);  NXa[cc][1] = MF(a1, bx, NXa[cc][1]);
          NXa[cc][0] = MF(a0, bxl,NXa[cc][0]);  NXa[cc][1] = MF(a1, bxl,NXa[cc][1]);
        }
      }
    }
#pragma unroll
    for (int cc = 0; cc < 2; ++cc) {
      const int c = cc ? c1 : c0;
      if (c < 0) continue;
#pragma unroll
      for (int rr = 0; rr < 2; ++rr)
#pragma unroll
        for (int i = 0; i < 4; ++i) {
          const float r = sigm(R[cc][rr][i]);
          const float z = sigm(Zx[cc][rr][i]);
          const float n = tanh_(NXa[cc][rr][i] + r * NHa[cc][rr][i]);
          hreg[cc][rr][i] = (1.f - z) * n + z * hreg[cc][rr][i];
        }
    }
    __syncthreads();
#pragma unroll
    for (int cc = 0; cc < 2; ++cc) {
      const int c = cc ? c1 : c0;
      if (c < 0) continue;
      const int d = 16 * c + cl;
      if (d < 100) {
#pragma unroll
        for (int rr = 0; rr < 2; ++rr)
#pragma unroll
          for (int i = 0; i < 4; ++i) {
            const int row = (rt0 + rr) * 16 + g4 * 4 + i;
            const ushort_t us = f2b(hreg[cc][rr][i]);
            Esh[t * 6400 + row * 100 + d] = us;
            stA16(Ash, row, (t < 9) ? d : 100 + d, us);
          }
      }
    }
    if (t < 9) onehot(encX, t + 1, 200);
    else       onehot(decX, 0, 400);
    __syncthreads();
  }

  // ================= decoder =================
  for (int t = 0; t < kS; ++t) {
    // ---- ph1: g = h @ attnW (MFMA) -> A ctx cols 0..99 ----
    {
      f32x4 G[2][2];
#pragma unroll
      for (int cc = 0; cc < 2; ++cc)
#pragma unroll
        for (int rr = 0; rr < 2; ++rr) G[cc][rr] = f32x4{0,0,0,0};
#pragma unroll
      for (int fi = 0; fi < 4; ++fi) {
        s16x8 a0 = ldA(Ash, rt0, 3 + fi, cl, g4);
        s16x8 a1 = ldA(Ash, rt0 + 1, 3 + fi, cl, g4);
#pragma unroll
        for (int cc = 0; cc < 2; ++cc) {
          const int c = cc ? c1 : c0;
          if (c < 0) continue;
          s16x8 bg = ldBF(WATT, c * 4 + fi, lane);
          G[cc][0] = MF(a0, bg, G[cc][0]);
          G[cc][1] = MF(a1, bg, G[cc][1]);
        }
      }
#pragma unroll
      for (int cc = 0; cc < 2; ++cc) {
        const int c = cc ? c1 : c0;
        if (c < 0) continue;
        const int d = 16 * c + cl;
        if (d < 100) {
#pragma unroll
          for (int rr = 0; rr < 2; ++rr)
#pragma unroll
            for (int i = 0; i < 4; ++i)
              stA16(Ash, (rt0 + rr) * 16 + g4 * 4 + i, d, f2b(G[cc][rr][i]));
        }
      }
    }
    __syncthreads();
    // ---- ph2: scores (wave w -> s=w; waves 0,1 also s=8,9) ----
    {
      auto score_task = [&](int s) {
        const ushort_t* ep = Esh + s * 6400 + lane * 100;
        float acc = 0.f;
#pragma unroll
        for (int jj = 0; jj < 25; ++jj) {
          uint2 gv = ldA64(Ash, lane, jj * 8);
          uint2 ev = *(const uint2*)(ep + jj * 4);
          acc += lo16(gv.x) * lo16(ev.x) + hi16(gv.x) * hi16(ev.x)
               + lo16(gv.y) * lo16(ev.y) + hi16(gv.y) * hi16(ev.y);
        }
        Ssh[lane * 10 + s] = acc;
      };
      score_task(w);
      if (w < 2) score_task(8 + w);
    }
    __syncthreads();
    // ---- ph3: softmax + ctx -> A ctx cols ----
    {
      float wat[10];
      {
        float sc[10];
#pragma unroll
        for (int s = 0; s < 10; ++s) sc[s] = Ssh[lane * 10 + s];
        float m = sc[0];
#pragma unroll
        for (int s = 1; s < 10; ++s) m = fmaxf(m, sc[s]);
        float sum = 0.f;
#pragma unroll
        for (int s = 0; s < 10; ++s) { wat[s] = __expf(sc[s] - m); sum += wat[s]; }
        const float inv = 1.f / sum;
#pragma unroll
        for (int s = 0; s < 10; ++s) wat[s] *= inv;
      }
      const int start = w * 12 + 2 * ((w < 2) ? w : 2);  // 0,14,28,40,52,64,76,88
      const int nu = (w < 2) ? 7 : 6;
#pragma unroll
      for (int u = 0; u < 7; ++u) {
        if (u < nu) {
          const int d0 = start + 2 * u;
          float v0 = 0.f, v1 = 0.f;
#pragma unroll
          for (int s = 0; s < 10; ++s) {
            const uint ev = *(const uint*)(Esh + s * 6400 + lane * 100 + d0);
            v0 += wat[s] * lo16(ev);
            v1 += wat[s] * hi16(ev);
          }
          stA32(Ash, lane, d0 * 2, (uint)f2b(v0) | ((uint)f2b(v1) << 16));
        }
      }
    }
    __syncthreads();
    // ---- ph4: GRU GEMMs + nonlin ----
    {
      f32x4 R[2][2], Zx[2][2], NC[2][2], NHa[2][2];
#pragma unroll
      for (int cc = 0; cc < 2; ++cc)
#pragma unroll
        for (int rr = 0; rr < 2; ++rr) {
          R[cc][rr] = f32x4{0,0,0,0}; Zx[cc][rr] = f32x4{0,0,0,0};
          NC[cc][rr] = f32x4{0,0,0,0}; NHa[cc][rr] = f32x4{0,0,0,0};
        }
#pragma unroll
      for (int kf = 0; kf < 8; ++kf) {
        s16x8 a0 = ldA(Ash, rt0, kf, cl, g4);
        s16x8 a1 = ldA(Ash, rt0 + 1, kf, cl, g4);
#pragma unroll
        for (int cc = 0; cc < 2; ++cc) {
          const int c = cc ? c1 : c0;
          if (c < 0) continue;
          s16x8 br = ldBF(BDR, c * 8 + kf, lane);
          s16x8 bz = ldBF(BDZ, c * 8 + kf, lane);
          R[cc][0]  = MF(a0, br, R[cc][0]);   R[cc][1]  = MF(a1, br, R[cc][1]);
          Zx[cc][0] = MF(a0, bz, Zx[cc][0]);  Zx[cc][1] = MF(a1, bz, Zx[cc][1]);
          if (kf < 4 || kf > 5) {
            const int fi = (kf < 4) ? kf : kf - 2;
            s16x8 bnc  = ldBF(BDNC,  c * 6 + fi, lane);
            s16x8 bncl = ldBF(BDNCL, c * 6 + fi, lane);
            NC[cc][0] = MF(a0, bnc, NC[cc][0]);  NC[cc][1] = MF(a1, bnc, NC[cc][1]);
            NC[cc][0] = MF(a0, bncl,NC[cc][0]);  NC[cc][1] = MF(a1, bncl,NC[cc][1]);
          }
          if (kf >= 3) {
            const int fi = kf - 3;
            s16x8 bnh  = ldBF(BDNH,  c * 5 + fi, lane);
            s16x8 bnhl = ldBF(BDNHL, c * 5 + fi, lane);
            NHa[cc][0] = MF(a0, bnh, NHa[cc][0]);  NHa[cc][1] = MF(a1, bnh, NHa[cc][1]);
            NHa[cc][0] = MF(a0, bnhl,NHa[cc][0]);  NHa[cc][1] = MF(a1, bnhl,NHa[cc][1]);
          }
        }
      }
#pragma unroll
      for (int cc = 0; cc < 2; ++cc) {
        const int c = cc ? c1 : c0;
        if (c < 0) continue;
#pragma unroll
        for (int rr = 0; rr < 2; ++rr)
#pragma unroll
          for (int i = 0; i < 4; ++i) {
            const float r = sigm(R[cc][rr][i]);
            const float z = sigm(Zx[cc][rr][i]);
            const float n = tanh_(NC[cc][rr][i] + r * NHa[cc][rr][i]);
            hreg[cc][rr][i] = (1.f - z) * n + z * hreg[cc][rr][i];
          }
      }
    }
    __syncthreads();
    // ---- ph5: h write + next onehot ----
#pragma unroll
    for (int cc = 0; cc < 2; ++cc) {
      const int c = cc ? c1 : c0;
      if (c < 0) continue;
      const int d = 16 * c + cl;
      if (d < 100) {
#pragma unroll
        for (int rr = 0; rr < 2; ++rr)
#pragma unroll
          for (int i = 0; i < 4; ++i)
            stA16(Ash, (rt0 + rr) * 16 + g4 * 4 + i, 100 + d, f2b(hreg[cc][rr][i]));
      }
    }
    if (t < 9) onehot(decX, t + 1, 400);
    __syncthreads();
    // ---- ph6: logits (wave -> (rt = w>>1, vtile = w&1)) ----
    {
      const int rtL = w >> 1, vt = w & 1;
      f32x4 aL = f32x4{0,0,0,0};
#pragma unroll
      for (int fi = 0; fi < 5; ++fi) {
        s16x8 a = ldA(Ash, rtL, 3 + fi, cl, g4);
        aL = MF(a, ldBF(BLIN,  vt * 5 + fi, lane), aL);
        aL = MF(a, ldBF(BLINL, vt * 5 + fi, lane), aL);
      }
      const int v = vt * 16 + cl;
      if (v < kV) {
#pragma unroll
        for (int i = 0; i < 4; ++i) {
          const int row = rtL * 16 + g4 * 4 + i;
          out[((size_t)(b0 + row) * kS + t) * kV + v] = aL[i];
        }
      }
    }
    __syncthreads();   // protect next ph1's A-writes vs ph6/ph1 A-reads
  }
}

extern "C" void kernel_launch(void* const* d_in, const int* in_sizes, int n_in,
                              void* d_out, int out_size, void* d_ws, size_t ws_size,
                              hipStream_t stream) {
  const int*   encX = (const int*)d_in[0];
  const int*   decX = (const int*)d_in[1];
  const float* emb  = (const float*)d_in[2];
  const float* eWih = (const float*)d_in[3];
  const float* eWhh = (const float*)d_in[4];
  const float* ebih = (const float*)d_in[5];
  const float* ebhh = (const float*)d_in[6];
  const float* dWih = (const float*)d_in[7];
  const float* dWhh = (const float*)d_in[8];
  const float* dbih = (const float*)d_in[9];
  const float* dbhh = (const float*)d_in[10];
  const float* attW = (const float*)d_in[11];
  const float* linW = (const float*)d_in[12];
  const float* linb = (const float*)d_in[13];
  ushort_t* ws = (ushort_t*)d_ws;
  float* o = (float*)d_out;

  seq2seq_setup<<<128, 256, 0, stream>>>(emb, eWih, eWhh, ebih, ebhh,
                                         dWih, dWhh, dbih, dbhh, attW, linW, linb, ws);
  seq2seq_main<<<NB, 512, 0, stream>>>(encX, decX, ws, o);
}

// Round 5
// 457.416 us; speedup vs baseline: 13.5665x; 2.2960x over previous
//
#include <hip/hip_runtime.h>
#include <hip/hip_bf16.h>

typedef short s16x8 __attribute__((ext_vector_type(8)));
typedef float f32x4 __attribute__((ext_vector_type(4)));
typedef unsigned short ushort_t;
typedef unsigned int uint;

#define DEV static __device__ __forceinline__

namespace {
constexpr int kV = 27, kS = 10, kB = 32768;
constexpr int BT = 64, NB = kB / BT;   // 512 blocks

// fragment-ordered blob offsets (ushort units): [(tile*nF+fi)*512 + lane*8 + e]
constexpr size_t O_BE_R   = 0;
constexpr size_t O_BE_Z   = O_BE_R   + (size_t)7*4*512;
constexpr size_t O_BE_NH  = O_BE_Z   + (size_t)7*4*512;
constexpr size_t O_BE_NHL = O_BE_NH  + (size_t)7*4*512;
constexpr size_t O_BE_NX  = O_BE_NHL + (size_t)7*4*512;
constexpr size_t O_BE_NXL = O_BE_NX  + (size_t)7*1*512;
constexpr size_t O_BD_R   = O_BE_NXL + (size_t)7*1*512;
constexpr size_t O_BD_Z   = O_BD_R   + (size_t)7*8*512;
constexpr size_t O_BD_NC  = O_BD_Z   + (size_t)7*8*512;   // frags {0,1,2,3,7}
constexpr size_t O_BD_NCL = O_BD_NC  + (size_t)7*5*512;
constexpr size_t O_BD_NH  = O_BD_NCL + (size_t)7*5*512;   // frags {4,5,6,7}
constexpr size_t O_BD_NHL = O_BD_NH  + (size_t)7*4*512;
constexpr size_t O_WATT   = O_BD_NHL + (size_t)7*4*512;   // frags {4,5,6,7}
constexpr size_t O_BLIN   = O_WATT   + (size_t)7*4*512;   // frags {4,5,6,7}
constexpr size_t O_BLINL  = O_BLIN   + (size_t)2*4*512;
} // namespace

DEV float sigm(float x) { return 1.f / (1.f + __expf(-x)); }
DEV float tanh_(float x) {
  const float ax = fabsf(x), t = __expf(-2.f * ax);
  return copysignf((1.f - t) / (1.f + t), x);
}
DEV ushort_t f2b(float f) { return __builtin_bit_cast(ushort_t, __float2bfloat16(f)); }
DEV float b2f(ushort_t u) { return __builtin_bit_cast(float, (uint)u << 16); }
DEV float lo16(uint u) { return __builtin_bit_cast(float, u << 16); }
DEV float hi16(uint u) { return __builtin_bit_cast(float, u & 0xFFFF0000u); }
DEV f32x4 MF(s16x8 a, s16x8 b, f32x4 c) {
  return __builtin_amdgcn_mfma_f32_16x16x32_bf16(a, b, c, 0, 0, 0);
}
DEV float dot64(const float* __restrict__ a, const float* __restrict__ b) {
  float s = 0.f;
#pragma unroll 16
  for (int k = 0; k < 64; ++k) s += a[k] * b[k];
  return s;
}
DEV void storeHL(ushort_t* ws, size_t offH, size_t offL, int e, float v) {
  const ushort_t h = f2b(v);
  ws[offH + e] = h;
  ws[offL + e] = f2b(v - b2f(h));
}

// fragment-ordered B load: one coalesced 1KB block per (tile,frag)
DEV s16x8 ldBF(const ushort_t* p, int fragIdx, int lane) {
  return __builtin_bit_cast(s16x8, *(const uint4*)(p + ((size_t)fragIdx << 9) + (lane << 3)));
}
// swizzled A-tile (row stride 512B, XOR (row&7)<<4)
DEV uint swzb(int row, int byteoff) { return (uint)((row * 512 + byteoff) ^ ((row & 7) << 4)); }
DEV s16x8 ldA(const ushort_t* A, int rt, int kf, int cl, int g4) {
  const int row = rt * 16 + cl;
  return __builtin_bit_cast(s16x8, *(const uint4*)((const char*)A + swzb(row, kf * 64 + g4 * 16)));
}
DEV void stA16(ushort_t* A, int row, int col, ushort_t v) {
  *(ushort_t*)((char*)A + swzb(row, col * 2)) = v;
}
DEV void stA32(ushort_t* A, int row, int byteoff, uint v) {
  *(uint*)((char*)A + swzb(row, byteoff)) = v;
}
DEV uint2 ldA64(const ushort_t* A, int row, int byteoff) {
  return *(const uint2*)((const char*)A + swzb(row, byteoff));
}

// ============ setup ============
// Encoder A (K=128): [h 0..99 | oh 100..126 | const1 @127]
// Decoder A (K=256): [ctx 0..99 | pad | h 128..227 | oh 228..254 | const1 @255]
__global__ void seq2seq_setup(const float* __restrict__ emb,
    const float* __restrict__ eWih, const float* __restrict__ eWhh,
    const float* __restrict__ ebih, const float* __restrict__ ebhh,
    const float* __restrict__ dWih, const float* __restrict__ dWhh,
    const float* __restrict__ dbih, const float* __restrict__ dbhh,
    const float* __restrict__ attnW, const float* __restrict__ linW,
    const float* __restrict__ linb, ushort_t* __restrict__ ws) {
  const int t0 = blockIdx.x * blockDim.x + threadIdx.x;
  const int stp = gridDim.x * blockDim.x;

  // BE_R / BE_Z / BE_NH(hi,lo): 7 tiles x frags 0..3
  for (int e = t0; e < 7 * 4 * 512; e += stp) {
    int c = e >> 11, rem = e & 2047, fi = rem >> 9, l = (rem >> 3) & 63, i8 = rem & 7;
    int d = 16 * c + (l & 15);
    int k = fi * 32 + ((l >> 4) << 3) + i8;
    float vr = 0, vz = 0, vnh = 0;
    if (d < 100) {
      if (k < 100) { vr = eWhh[d*100+k]; vz = eWhh[(100+d)*100+k]; vnh = eWhh[(200+d)*100+k]; }
      else if (k < 127) {
        int tok = k - 100;
        vr = dot64(emb + tok*64, eWih + (size_t)d*64);
        vz = dot64(emb + tok*64, eWih + (size_t)(100+d)*64);
      } else { // const-1
        vr = ebih[d] + ebhh[d]; vz = ebih[100+d] + ebhh[100+d]; vnh = ebhh[200+d];
      }
    }
    ws[O_BE_R + e] = f2b(vr);
    ws[O_BE_Z + e] = f2b(vz);
    storeHL(ws, O_BE_NH, O_BE_NHL, e, vnh);
  }
  // BE_NX(hi,lo): 7 tiles x frag {3}
  for (int e = t0; e < 7 * 512; e += stp) {
    int c = e >> 9, l = (e >> 3) & 63, i8 = e & 7;
    int d = 16 * c + (l & 15);
    int k = 96 + ((l >> 4) << 3) + i8;
    float v = 0;
    if (d < 100) {
      if (k >= 100 && k < 127) v = dot64(emb + (k-100)*64, eWih + (size_t)(200+d)*64);
      else if (k == 127) v = ebih[200+d];
    }
    storeHL(ws, O_BE_NX, O_BE_NXL, e, v);
  }
  // BD_R / BD_Z: 7 tiles x frags 0..7
  for (int e = t0; e < 7 * 8 * 512; e += stp) {
    int c = e >> 12, rem = e & 4095, fi = rem >> 9, l = (rem >> 3) & 63, i8 = rem & 7;
    int d = 16 * c + (l & 15);
    int k = fi * 32 + ((l >> 4) << 3) + i8;
    float vr = 0, vz = 0;
    if (d < 100) {
      int wr = d, wz = 100 + d;
      if (k < 100)       { vr = dWih[(size_t)wr*164+64+k]; vz = dWih[(size_t)wz*164+64+k]; }
      else if (k < 128)  { }
      else if (k < 228)  { vr = dWhh[wr*100+k-128];        vz = dWhh[wz*100+k-128]; }
      else if (k < 255)  { vr = dot64(emb+(k-228)*64, dWih+(size_t)wr*164);
                           vz = dot64(emb+(k-228)*64, dWih+(size_t)wz*164); }
      else               { vr = dbih[wr]+dbhh[wr];         vz = dbih[wz]+dbhh[wz]; }
    }
    ws[O_BD_R + e] = f2b(vr);
    ws[O_BD_Z + e] = f2b(vz);
  }
  // BD_NC(hi,lo): 7 tiles x frags {0,1,2,3,7}
  for (int e = t0; e < 7 * 5 * 512; e += stp) {
    int c = e / (5*512), rem = e - c*5*512, fi = rem >> 9, l = (rem >> 3) & 63, i8 = rem & 7;
    int fid = (fi < 4) ? fi : 7;
    int d = 16 * c + (l & 15);
    int k = fid * 32 + ((l >> 4) << 3) + i8;
    float v = 0;
    if (d < 100) {
      int wr = 200 + d;
      if (k < 100) v = dWih[(size_t)wr*164+64+k];
      else if (k >= 228 && k < 255) v = dot64(emb+(k-228)*64, dWih+(size_t)wr*164);
      else if (k == 255) v = dbih[wr];
    }
    storeHL(ws, O_BD_NC, O_BD_NCL, e, v);
  }
  // BD_NH(hi,lo): 7 tiles x frags {4,5,6,7}
  for (int e = t0; e < 7 * 4 * 512; e += stp) {
    int c = e >> 11, rem = e & 2047, fi = rem >> 9, l = (rem >> 3) & 63, i8 = rem & 7;
    int d = 16 * c + (l & 15);
    int k = (4 + fi) * 32 + ((l >> 4) << 3) + i8;
    float v = 0;
    if (d < 100) {
      int wr = 200 + d;
      if (k >= 128 && k < 228) v = dWhh[wr*100+k-128];
      else if (k == 255) v = dbhh[wr];
    }
    storeHL(ws, O_BD_NH, O_BD_NHL, e, v);
  }
  // WATT: 7 tiles x frags {4,5,6,7}
  for (int e = t0; e < 7 * 4 * 512; e += stp) {
    int c = e >> 11, rem = e & 2047, fi = rem >> 9, l = (rem >> 3) & 63, i8 = rem & 7;
    int d = 16 * c + (l & 15);
    int k = (4 + fi) * 32 + ((l >> 4) << 3) + i8;
    float v = 0;
    if (d < 100 && k >= 128 && k < 228) v = attnW[(k-128)*100 + d];
    ws[O_WATT + e] = f2b(v);
  }
  // BLIN(hi,lo): 2 tiles x frags {4,5,6,7}
  for (int e = t0; e < 2 * 4 * 512; e += stp) {
    int c = e >> 11, rem = e & 2047, fi = rem >> 9, l = (rem >> 3) & 63, i8 = rem & 7;
    int vv = 16 * c + (l & 15);
    int k = (4 + fi) * 32 + ((l >> 4) << 3) + i8;
    float v = 0;
    if (vv < kV) {
      if (k >= 128 && k < 228) v = linW[vv*100 + k-128];
      else if (k == 255) v = linb[vv];
    }
    storeHL(ws, O_BLIN, O_BLINL, e, v);
  }
}

// ============ fused main: 512 thr = 8 waves; waves 0..6 own col-tile c=w (all 4 row-tiles) ============
__global__ __launch_bounds__(512, 1)
void seq2seq_main(const int* __restrict__ encX, const int* __restrict__ decX,
                  const ushort_t* __restrict__ ws, float* __restrict__ out) {
  const int tid  = threadIdx.x;
  const int lane = tid & 63;
  const int w    = __builtin_amdgcn_readfirstlane(tid >> 6);
  const int cl   = lane & 15, g4 = lane >> 4;
  const int c    = w;                      // col-tile (valid w<7)
  const int b0   = blockIdx.x * BT;

  __shared__ alignas(16) ushort_t Ash[BT * 256];        // 32,768 B swizzled
  __shared__ alignas(16) ushort_t Esh[10 * BT * 100];   // 128,000 B enc_out bf16
  __shared__ alignas(16) float    Ssh[BT * 10];         // 2,560 B

  const ushort_t* BER   = ws + O_BE_R;
  const ushort_t* BEZ   = ws + O_BE_Z;
  const ushort_t* BENH  = ws + O_BE_NH;
  const ushort_t* BENHL = ws + O_BE_NHL;
  const ushort_t* BENX  = ws + O_BE_NX;
  const ushort_t* BENXL = ws + O_BE_NXL;
  const ushort_t* BDR   = ws + O_BD_R;
  const ushort_t* BDZ   = ws + O_BD_Z;
  const ushort_t* BDNC  = ws + O_BD_NC;
  const ushort_t* BDNCL = ws + O_BD_NCL;
  const ushort_t* BDNH  = ws + O_BD_NH;
  const ushort_t* BDNHL = ws + O_BD_NHL;
  const ushort_t* WATT  = ws + O_WATT;
  const ushort_t* BLIN  = ws + O_BLIN;
  const ushort_t* BLINL = ws + O_BLINL;

  float hreg[4][4];   // wave's 16 dims x 64 rows (4 rt x 4 i per lane)
#pragma unroll
  for (int rt = 0; rt < 4; ++rt)
#pragma unroll
    for (int i = 0; i < 4; ++i) hreg[rt][i] = 0.f;

  auto onehot = [&](const int* X, int tt, int baseByte) {
    if (w < 4) {
      const int tok = X[(b0 + lane) * kS + tt];
#pragma unroll
      for (int p = 0; p < 4; ++p) {
        const int j0 = w * 8 + 2 * p;
        if (j0 <= 26) {
          const uint lo = (j0 == tok || j0 == 27) ? 0x3F80u : 0u;
          const uint hi = (j0 + 1 == tok || j0 + 1 == 27) ? 0x3F80u : 0u;
          stA32(Ash, lane, baseByte + j0 * 2, lo | (hi << 16));
        }
      }
    }
  };

  for (int i = tid; i < BT * 256 / 2; i += 512) ((uint*)Ash)[i] = 0u;
  __syncthreads();
  onehot(encX, 0, 200);
  __syncthreads();

  // ================= encoder =================
  for (int t = 0; t < kS; ++t) {
    if (w < 7) {
      f32x4 R[4], Zx[4], NHa[4], NXa[4];
#pragma unroll
      for (int rt = 0; rt < 4; ++rt) {
        R[rt] = f32x4{0,0,0,0}; Zx[rt] = f32x4{0,0,0,0};
        NHa[rt] = f32x4{0,0,0,0}; NXa[rt] = f32x4{0,0,0,0};
      }
#pragma unroll
      for (int kf = 0; kf < 4; ++kf) {
        s16x8 a[4];
#pragma unroll
        for (int rt = 0; rt < 4; ++rt) a[rt] = ldA(Ash, rt, kf, cl, g4);
        s16x8 br  = ldBF(BER,   c * 4 + kf, lane);
        s16x8 bz  = ldBF(BEZ,   c * 4 + kf, lane);
        s16x8 bh  = ldBF(BENH,  c * 4 + kf, lane);
        s16x8 bhl = ldBF(BENHL, c * 4 + kf, lane);
#pragma unroll
        for (int rt = 0; rt < 4; ++rt) {
          R[rt]   = MF(a[rt], br, R[rt]);
          Zx[rt]  = MF(a[rt], bz, Zx[rt]);
          NHa[rt] = MF(a[rt], bh, NHa[rt]);
          NHa[rt] = MF(a[rt], bhl, NHa[rt]);
        }
        if (kf == 3) {
          s16x8 bx  = ldBF(BENX,  c, lane);
          s16x8 bxl = ldBF(BENXL, c, lane);
#pragma unroll
          for (int rt = 0; rt < 4; ++rt) {
            NXa[rt] = MF(a[rt], bx, NXa[rt]);
            NXa[rt] = MF(a[rt], bxl, NXa[rt]);
          }
        }
      }
#pragma unroll
      for (int rt = 0; rt < 4; ++rt)
#pragma unroll
        for (int i = 0; i < 4; ++i) {
          const float r = sigm(R[rt][i]);
          const float z = sigm(Zx[rt][i]);
          const float n = tanh_(NXa[rt][i] + r * NHa[rt][i]);
          hreg[rt][i] = (1.f - z) * n + z * hreg[rt][i];
        }
    }
    __syncthreads();
    if (w < 7) {
      const int d = 16 * c + cl;
      if (d < 100) {
#pragma unroll
        for (int rt = 0; rt < 4; ++rt)
#pragma unroll
          for (int i = 0; i < 4; ++i) {
            const int row = rt * 16 + g4 * 4 + i;
            const ushort_t us = f2b(hreg[rt][i]);
            Esh[t * 6400 + row * 100 + d] = us;
            stA16(Ash, row, (t < 9) ? d : 128 + d, us);
          }
      }
    }
    if (t < 9) onehot(encX, t + 1, 200);
    else       onehot(decX, 0, 456);
    __syncthreads();
  }

  // ================= decoder =================
  for (int t = 0; t < kS; ++t) {
    // ---- ph1: g = h @ attnW -> A cols 0..99 ----
    if (w < 7) {
      f32x4 G[4] = {f32x4{0,0,0,0}, f32x4{0,0,0,0}, f32x4{0,0,0,0}, f32x4{0,0,0,0}};
#pragma unroll
      for (int fi = 0; fi < 4; ++fi) {
        s16x8 bg = ldBF(WATT, c * 4 + fi, lane);
#pragma unroll
        for (int rt = 0; rt < 4; ++rt)
          G[rt] = MF(ldA(Ash, rt, 4 + fi, cl, g4), bg, G[rt]);
      }
      const int d = 16 * c + cl;
      if (d < 100) {
#pragma unroll
        for (int rt = 0; rt < 4; ++rt)
#pragma unroll
          for (int i = 0; i < 4; ++i)
            stA16(Ash, rt * 16 + g4 * 4 + i, d, f2b(G[rt][i]));
      }
    }
    __syncthreads();
    // ---- ph2: scores ----
    {
      auto score_task = [&](int s) {
        const ushort_t* ep = Esh + s * 6400 + lane * 100;
        float acc = 0.f;
#pragma unroll
        for (int jj = 0; jj < 25; ++jj) {
          uint2 gv = ldA64(Ash, lane, jj * 8);
          uint2 ev = *(const uint2*)(ep + jj * 4);
          acc += lo16(gv.x) * lo16(ev.x) + hi16(gv.x) * hi16(ev.x)
               + lo16(gv.y) * lo16(ev.y) + hi16(gv.y) * hi16(ev.y);
        }
        Ssh[lane * 10 + s] = acc;
      };
      score_task(w);
      if (w < 2) score_task(8 + w);
    }
    __syncthreads();
    // ---- ph3: softmax + ctx -> A cols 0..99 ----
    {
      float wat[10];
      {
        float sc[10];
#pragma unroll
        for (int s = 0; s < 10; ++s) sc[s] = Ssh[lane * 10 + s];
        float m = sc[0];
#pragma unroll
        for (int s = 1; s < 10; ++s) m = fmaxf(m, sc[s]);
        float sum = 0.f;
#pragma unroll
        for (int s = 0; s < 10; ++s) { wat[s] = __expf(sc[s] - m); sum += wat[s]; }
        const float inv = 1.f / sum;
#pragma unroll
        for (int s = 0; s < 10; ++s) wat[s] *= inv;
      }
      const int start = w * 12 + 2 * ((w < 2) ? w : 2);  // 0,14,28,40,52,64,76,88
      const int nu = (w < 2) ? 7 : 6;
#pragma unroll
      for (int u = 0; u < 7; ++u) {
        if (u < nu) {
          const int d0 = start + 2 * u;
          float v0 = 0.f, v1 = 0.f;
#pragma unroll
          for (int s = 0; s < 10; ++s) {
            const uint ev = *(const uint*)(Esh + s * 6400 + lane * 100 + d0);
            v0 += wat[s] * lo16(ev);
            v1 += wat[s] * hi16(ev);
          }
          stA32(Ash, lane, d0 * 2, (uint)f2b(v0) | ((uint)f2b(v1) << 16));
        }
      }
    }
    __syncthreads();
    // ---- ph4: GRU GEMMs + nonlin ----
    if (w < 7) {
      f32x4 R[4], Zx[4], NC[4], NHa[4];
#pragma unroll
      for (int rt = 0; rt < 4; ++rt) {
        R[rt] = f32x4{0,0,0,0}; Zx[rt] = f32x4{0,0,0,0};
        NC[rt] = f32x4{0,0,0,0}; NHa[rt] = f32x4{0,0,0,0};
      }
#pragma unroll
      for (int kf = 0; kf < 8; ++kf) {
        s16x8 a[4];
#pragma unroll
        for (int rt = 0; rt < 4; ++rt) a[rt] = ldA(Ash, rt, kf, cl, g4);
        s16x8 br = ldBF(BDR, c * 8 + kf, lane);
        s16x8 bz = ldBF(BDZ, c * 8 + kf, lane);
#pragma unroll
        for (int rt = 0; rt < 4; ++rt) {
          R[rt]  = MF(a[rt], br, R[rt]);
          Zx[rt] = MF(a[rt], bz, Zx[rt]);
        }
        if (kf < 4 || kf == 7) {
          const int fi = (kf < 4) ? kf : 4;
          s16x8 bnc  = ldBF(BDNC,  c * 5 + fi, lane);
          s16x8 bncl = ldBF(BDNCL, c * 5 + fi, lane);
#pragma unroll
          for (int rt = 0; rt < 4; ++rt) {
            NC[rt] = MF(a[rt], bnc, NC[rt]);
            NC[rt] = MF(a[rt], bncl, NC[rt]);
          }
        }
        if (kf >= 4) {
          const int fi = kf - 4;
          s16x8 bnh  = ldBF(BDNH,  c * 4 + fi, lane);
          s16x8 bnhl = ldBF(BDNHL, c * 4 + fi, lane);
#pragma unroll
          for (int rt = 0; rt < 4; ++rt) {
            NHa[rt] = MF(a[rt], bnh, NHa[rt]);
            NHa[rt] = MF(a[rt], bnhl, NHa[rt]);
          }
        }
      }
#pragma unroll
      for (int rt = 0; rt < 4; ++rt)
#pragma unroll
        for (int i = 0; i < 4; ++i) {
          const float r = sigm(R[rt][i]);
          const float z = sigm(Zx[rt][i]);
          const float n = tanh_(NC[rt][i] + r * NHa[rt][i]);
          hreg[rt][i] = (1.f - z) * n + z * hreg[rt][i];
        }
    }
    __syncthreads();
    // ---- ph5: h write (cols 128..227) + next onehot ----
    if (w < 7) {
      const int d = 16 * c + cl;
      if (d < 100) {
#pragma unroll
        for (int rt = 0; rt < 4; ++rt)
#pragma unroll
          for (int i = 0; i < 4; ++i)
            stA16(Ash, rt * 16 + g4 * 4 + i, 128 + d, f2b(hreg[rt][i]));
      }
    }
    if (t < 9) onehot(decX, t + 1, 456);
    __syncthreads();
    // ---- ph6: logits (8 wave-tasks), nontemporal stores; no trailing sync (disjoint vs next ph1) ----
    {
      const int rtL = w >> 1, vt = w & 1;
      f32x4 aL = f32x4{0,0,0,0};
#pragma unroll
      for (int fi = 0; fi < 4; ++fi) {
        s16x8 a = ldA(Ash, rtL, 4 + fi, cl, g4);
        aL = MF(a, ldBF(BLIN,  vt * 4 + fi, lane), aL);
        aL = MF(a, ldBF(BLINL, vt * 4 + fi, lane), aL);
      }
      const int v = vt * 16 + cl;
      if (v < kV) {
#pragma unroll
        for (int i = 0; i < 4; ++i) {
          const int row = rtL * 16 + g4 * 4 + i;
          __builtin_nontemporal_store(aL[i], &out[((size_t)(b0 + row) * kS + t) * kV + v]);
        }
      }
    }
  }
}

extern "C" void kernel_launch(void* const* d_in, const int* in_sizes, int n_in,
                              void* d_out, int out_size, void* d_ws, size_t ws_size,
                              hipStream_t stream) {
  const int*   encX = (const int*)d_in[0];
  const int*   decX = (const int*)d_in[1];
  const float* emb  = (const float*)d_in[2];
  const float* eWih = (const float*)d_in[3];
  const float* eWhh = (const float*)d_in[4];
  const float* ebih = (const float*)d_in[5];
  const float* ebhh = (const float*)d_in[6];
  const float* dWih = (const float*)d_in[7];
  const float* dWhh = (const float*)d_in[8];
  const float* dbih = (const float*)d_in[9];
  const float* dbhh = (const float*)d_in[10];
  const float* attW = (const float*)d_in[11];
  const float* linW = (const float*)d_in[12];
  const float* linb = (const float*)d_in[13];
  ushort_t* ws = (ushort_t*)d_ws;
  float* o = (float*)d_out;

  seq2seq_setup<<<128, 256, 0, stream>>>(emb, eWih, eWhh, ebih, ebhh,
                                         dWih, dWhh, dbih, dbhh, attW, linW, linb, ws);
  seq2seq_main<<<NB, 512, 0, stream>>>(encX, decX, ws, o);
}